// Round 4
// baseline (157.736 us; speedup 1.0000x reference)
//
#include <hip/hip_runtime.h>
#include <math.h>

#define B_SZ 1024
#define Z_DIM 512
#define A_DIM 8
#define AH 64
#define ZH 512
#define NNEG 99
#define ROWLEN (B_SZ + NNEG)  // 1123
#define INV_T 10.0f

typedef __attribute__((ext_vector_type(8))) short short8;   // 8 bf16
typedef __attribute__((ext_vector_type(4))) short short4_t; // 4 bf16
typedef __attribute__((ext_vector_type(4))) float f32x4;

// fp32 -> bf16 hi (truncate) + bf16 lo (residual). x ~= hi + lo, rel err < 2^-16.
__device__ __forceinline__ void cvt4(float4 x, short4_t& hi, short4_t& lo) {
    float xs[4] = {x.x, x.y, x.z, x.w};
#pragma unroll
    for (int i = 0; i < 4; ++i) {
        unsigned uu = __float_as_uint(xs[i]);
        hi[i] = (short)(uu >> 16);
        float hf = __uint_as_float(uu & 0xffff0000u);
        lo[i] = (short)(__float_as_uint(xs[i] - hf) >> 16);
    }
}

struct MfmaSmem { short Ah[64][72]; short Al[64][72]; short Bh[64][72]; short Bl[64][72]; };
struct Seg3Smem {
    float LA[32][68]; float LB[32][68];
    float sact[64][A_DIM]; float sWa[A_DIM * AH]; float sba[AH];
};

// ---------------------------------------------------------------------------
// 640 blocks:
//   seg0 [  0,256): sim = z_next @ z_next_hat^T   (MFMA NT)
//   seg1 [256,384): u   = z @ W1[:512,:] + b1     (MFMA NN, LDS transpose)
//   seg2 [384,512): v   = z_next @ W2^T           (MFMA NT)
//   seg3 [512,640): g   = relu(actions@Wa+ba)@W1h (fp32 vector, K=64)
// MFMA: 64x64 block tile, 4 waves x (32x32 via 2x2 of 16x16x32 bf16),
// 3-term hi/lo split, conversion done ONCE at staging into bf16 LDS.
__global__ __launch_bounds__(256) void fused_gemm(
    const float* __restrict__ z, const float* __restrict__ z_next,
    const float* __restrict__ z_next_hat, const float* __restrict__ actions,
    const float* __restrict__ Wa, const float* __restrict__ ba,
    const float* __restrict__ W1, const float* __restrict__ b1,
    const float* __restrict__ W2,
    float* __restrict__ sim, float* __restrict__ u, float* __restrict__ v,
    float* __restrict__ g, unsigned* __restrict__ cnt)
{
    __shared__ union { MfmaSmem m; Seg3Smem s; } sm;

    const int id = blockIdx.x;
    const int tid = threadIdx.x;
    if (id == 0 && tid == 0) *cnt = 0;

    // ================= seg3: g (fp32 vector path, K=64) =================
    if (id >= 512) {
        int t = id - 512;
        int bn0 = (t & 7) * 64, bm0 = (t >> 3) * 64;
        const float* W1h = W1 + Z_DIM * ZH;
        for (int i = tid; i < 64 * A_DIM; i += 256)
            (&sm.s.sact[0][0])[i] = actions[bm0 * A_DIM + i];
        for (int i = tid; i < A_DIM * AH; i += 256) sm.s.sWa[i] = Wa[i];
        if (tid < AH) sm.s.sba[tid] = ba[tid];
        __syncthreads();
        int tm = (tid >> 4) << 2, tn = (tid & 15) << 2;
        float acc[4][4] = {};
        for (int k0 = 0; k0 < 64; k0 += 32) {
#pragma unroll
            for (int i = 0; i < 8; ++i) {           // A-tile gen: LA[k][m]
                int lin = tid + i * 256;
                int c = lin & 31, r = lin >> 5;
                int kc = k0 + c;
                float val = sm.s.sba[kc];
#pragma unroll
                for (int k = 0; k < A_DIM; ++k) val += sm.s.sact[r][k] * sm.s.sWa[k * AH + kc];
                sm.s.LA[c][r] = fmaxf(val, 0.0f);
            }
#pragma unroll
            for (int i = 0; i < 2; ++i) {           // B-tile: LB[k][n]
                int f = tid + i * 256;
                int r = f >> 4, c = (f & 15) * 4;
                *(float4*)&sm.s.LB[r][c] = *(const float4*)&W1h[(k0 + r) * ZH + bn0 + c];
            }
            __syncthreads();
#pragma unroll
            for (int k = 0; k < 32; ++k) {
                float4 a4 = *(const float4*)&sm.s.LA[k][tm];
                float4 b4 = *(const float4*)&sm.s.LB[k][tn];
                float a[4] = {a4.x, a4.y, a4.z, a4.w};
                float b[4] = {b4.x, b4.y, b4.z, b4.w};
#pragma unroll
                for (int i = 0; i < 4; ++i)
#pragma unroll
                    for (int j = 0; j < 4; ++j) acc[i][j] += a[i] * b[j];
            }
            __syncthreads();
        }
#pragma unroll
        for (int i = 0; i < 4; ++i) {
            float4 o = {acc[i][0], acc[i][1], acc[i][2], acc[i][3]};
            *(float4*)&g[(bm0 + tm + i) * ZH + bn0 + tn] = o;
        }
        return;
    }

    // ================= MFMA segs =================
    const float* Aop; const float* Bop; const float* bias = nullptr;
    float* C; int N; bool btrans; int bm0, bn0;
    if (id < 256) {
        int t = id; bn0 = (t & 15) * 64; bm0 = (t >> 4) * 64;
        Aop = z_next; Bop = z_next_hat; C = sim; N = 1024; btrans = true;
    } else if (id < 384) {
        int t = id - 256; bn0 = (t & 7) * 64; bm0 = (t >> 3) * 64;
        Aop = z; Bop = W1; C = u; N = 512; btrans = false; bias = b1;
    } else {
        int t = id - 384; bn0 = (t & 7) * 64; bm0 = (t >> 3) * 64;
        Aop = z_next; Bop = W2; C = v; N = 512; btrans = true;
    }

    const int lane = tid & 63, wv = tid >> 6;
    const int lm = lane & 15, lq = lane >> 4;
    const int wm = (wv >> 1) * 32, wn = (wv & 1) * 32;
    f32x4 acc[2][2] = {};

    for (int k0 = 0; k0 < 512; k0 += 64) {
        // stage A -> bf16 hi/lo LDS (convert once)
#pragma unroll
        for (int i = 0; i < 4; ++i) {
            int gg = tid + i * 256;
            int r = gg >> 4, c4 = (gg & 15) << 2;
            float4 av = *(const float4*)&Aop[(bm0 + r) * 512 + k0 + c4];
            short4_t hi, lo; cvt4(av, hi, lo);
            *(short4_t*)&sm.m.Ah[r][c4] = hi;
            *(short4_t*)&sm.m.Al[r][c4] = lo;
        }
        if (btrans) {
#pragma unroll
            for (int i = 0; i < 4; ++i) {
                int gg = tid + i * 256;
                int r = gg >> 4, c4 = (gg & 15) << 2;
                float4 bv = *(const float4*)&Bop[(bn0 + r) * 512 + k0 + c4];
                short4_t hi, lo; cvt4(bv, hi, lo);
                *(short4_t*)&sm.m.Bh[r][c4] = hi;
                *(short4_t*)&sm.m.Bl[r][c4] = lo;
            }
        } else {  // k-major (W1): transpose during staging
#pragma unroll
            for (int i = 0; i < 4; ++i) {
                int gg = tid + i * 256;
                int kr = gg >> 4, n4 = (gg & 15) << 2;
                float4 w = *(const float4*)&Bop[(k0 + kr) * 512 + bn0 + n4];
                short4_t hi, lo; cvt4(w, hi, lo);
#pragma unroll
                for (int e = 0; e < 4; ++e) {
                    sm.m.Bh[n4 + e][kr] = hi[e];
                    sm.m.Bl[n4 + e][kr] = lo[e];
                }
            }
        }
        __syncthreads();
#pragma unroll
        for (int kk = 0; kk < 64; kk += 32) {
            int kb = kk + lq * 8;
            short8 ah[2], al[2], bh[2], bl[2];
#pragma unroll
            for (int i = 0; i < 2; ++i) {
                ah[i] = *(const short8*)&sm.m.Ah[wm + i * 16 + lm][kb];
                al[i] = *(const short8*)&sm.m.Al[wm + i * 16 + lm][kb];
                bh[i] = *(const short8*)&sm.m.Bh[wn + i * 16 + lm][kb];
                bl[i] = *(const short8*)&sm.m.Bl[wn + i * 16 + lm][kb];
            }
#pragma unroll
            for (int i = 0; i < 2; ++i)
#pragma unroll
                for (int j = 0; j < 2; ++j) {
                    acc[i][j] = __builtin_amdgcn_mfma_f32_16x16x32_bf16(ah[i], bh[j], acc[i][j], 0, 0, 0);
                    acc[i][j] = __builtin_amdgcn_mfma_f32_16x16x32_bf16(ah[i], bl[j], acc[i][j], 0, 0, 0);
                    acc[i][j] = __builtin_amdgcn_mfma_f32_16x16x32_bf16(al[i], bh[j], acc[i][j], 0, 0, 0);
                }
        }
        __syncthreads();
    }
    // epilogue: C layout col=lane&15, row=(lane>>4)*4+reg
#pragma unroll
    for (int i = 0; i < 2; ++i)
#pragma unroll
        for (int j = 0; j < 2; ++j) {
            int n = bn0 + wn + j * 16 + lm;
            float bb = bias ? bias[n] : 0.0f;
#pragma unroll
            for (int r = 0; r < 4; ++r) {
                int m = bm0 + wm + i * 16 + lq * 4 + r;
                C[m * N + n] = acc[i][j][r] + bb;
            }
        }
}

// ---------------------------------------------------------------------------
// Per-row fused kernel + last-block finalize.
__global__ __launch_bounds__(256) void row_kernel(const float* __restrict__ sim,
                                                  const float* __restrict__ u,
                                                  const float* __restrict__ v,
                                                  const float* __restrict__ g,
                                                  const float* __restrict__ z,
                                                  const float* __restrict__ z_next,
                                                  const float* __restrict__ b2,
                                                  float* __restrict__ pw,
                                                  unsigned* __restrict__ cnt,
                                                  float* __restrict__ out) {
    int b = blockIdx.x;
    int tid = threadIdx.x;
    int wave = tid >> 6, lane = tid & 63;
    __shared__ float row[ROWLEN];
    __shared__ float redc0[4], redmax[4], redes[4];
    __shared__ int redcnt[4];
    __shared__ float red[256];
    __shared__ int sdone;

    // stage sim row
    *(float4*)&row[tid * 4] = ((const float4*)(sim + b * B_SZ))[tid];

    // per-lane u,v fragments in registers (elems 4*lane.. and 256+4*lane..)
    const float4* u4 = (const float4*)(u + b * ZH);
    const float4* v4 = (const float4*)(v + b * ZH);
    float4 uva = u4[lane], uvb = u4[lane + 64];
    float4 vva = v4[lane], vvb = v4[lane + 64];

    // c0 = (z[b]+b2)·z_next[b]
    float p = 0.0f;
    if (tid < 128) {
        const float4* z4 = (const float4*)(z + b * Z_DIM);
        const float4* zn4 = (const float4*)(z_next + b * Z_DIM);
        const float4* b24 = (const float4*)b2;
        float4 a = z4[tid], c = b24[tid], n = zn4[tid];
        p = (a.x + c.x) * n.x + (a.y + c.y) * n.y + (a.z + c.z) * n.z + (a.w + c.w) * n.w;
    }
    for (int off = 32; off; off >>= 1) p += __shfl_down(p, off);
    if (lane == 0) redc0[wave] = p;
    __syncthreads();
    float c0 = redc0[0] + redc0[1] + redc0[2] + redc0[3];

    // shift loop: wave w owns s = 1+w, 1+w+4, ...; 4-way ILP
    const float4* g4 = (const float4*)g;
    int nIter = (wave < 3) ? 25 : 24;
    for (int i0 = 0; i0 < nIter; i0 += 4) {
        int nact = nIter - i0; if (nact > 4) nact = 4;
        float4 ga[4], gb[4];
        int ss[4];
#pragma unroll
        for (int j = 0; j < 4; ++j) {
            int s = 1 + wave + 4 * (i0 + j);
            ss[j] = s;
            int se = (j < nact) ? s : 1;
            int jr = (b + se) & (B_SZ - 1);
            ga[j] = g4[jr * 128 + lane];
            gb[j] = g4[jr * 128 + 64 + lane];
        }
        float d[4];
#pragma unroll
        for (int j = 0; j < 4; ++j) {
            float t = 0.0f;
            t += fmaxf(uva.x + ga[j].x, 0.0f) * vva.x;
            t += fmaxf(uva.y + ga[j].y, 0.0f) * vva.y;
            t += fmaxf(uva.z + ga[j].z, 0.0f) * vva.z;
            t += fmaxf(uva.w + ga[j].w, 0.0f) * vva.w;
            t += fmaxf(uvb.x + gb[j].x, 0.0f) * vvb.x;
            t += fmaxf(uvb.y + gb[j].y, 0.0f) * vvb.y;
            t += fmaxf(uvb.z + gb[j].z, 0.0f) * vvb.z;
            t += fmaxf(uvb.w + gb[j].w, 0.0f) * vvb.w;
            d[j] = t;
        }
        for (int off = 32; off; off >>= 1) {
#pragma unroll
            for (int j = 0; j < 4; ++j) d[j] += __shfl_down(d[j], off);
        }
        if (lane == 0) {
#pragma unroll
            for (int j = 0; j < 4; ++j)
                if (j < nact) row[B_SZ + ss[j] - 1] = c0 + d[j];
        }
    }
    __syncthreads();

    float diag = row[b];
    float m = -3.4e38f;
    for (int j = tid; j < ROWLEN; j += 256) m = fmaxf(m, row[j]);
    for (int off = 32; off; off >>= 1) m = fmaxf(m, __shfl_down(m, off));
    if (lane == 0) redmax[wave] = m;
    __syncthreads();
    m = fmaxf(fmaxf(redmax[0], redmax[1]), fmaxf(redmax[2], redmax[3]));

    float es = 0.0f;
    int cntk = 0;
    for (int j = tid; j < ROWLEN; j += 256) {
        float x = row[j];
        es += __expf((x - m) * INV_T);
        if (x > diag) cntk++;
        else if (j < b && x == diag) cntk++;   // tie-break: lower index wins
    }
    for (int off = 32; off; off >>= 1) {
        es += __shfl_down(es, off);
        cntk += __shfl_down(cntk, off);
    }
    __syncthreads();
    if (lane == 0) { redes[wave] = es; redcnt[wave] = cntk; }
    __syncthreads();
    if (tid == 0) {
        float esum = redes[0] + redes[1] + redes[2] + redes[3];
        int rank = redcnt[0] + redcnt[1] + redcnt[2] + redcnt[3];
        float loss_b = (m - diag) * INV_T + logf(esum);
        pw[b * 4 + 0] = loss_b;
        pw[b * 4 + 1] = (rank < 1) ? 1.0f : 0.0f;
        pw[b * 4 + 2] = (rank < 3) ? 1.0f : 0.0f;
        pw[b * 4 + 3] = (rank < 10) ? 1.0f : 0.0f;
        __threadfence();
        unsigned old = atomicAdd(cnt, 1u);
        sdone = (old == B_SZ - 1) ? 1 : 0;
    }
    __syncthreads();
    if (sdone) {
        __threadfence();
        int c = tid & 3;
        float s = 0.0f;
        for (int r = tid >> 2; r < B_SZ; r += 64) s += pw[r * 4 + c];
        red[tid] = s;
        __syncthreads();
        if (tid < 4) {
            float t = 0.0f;
            for (int gg = 0; gg < 64; ++gg) t += red[tid + gg * 4];
            out[tid] = t * (1.0f / (float)B_SZ);
        }
    }
}

// ---------------------------------------------------------------------------
extern "C" void kernel_launch(void* const* d_in, const int* in_sizes, int n_in,
                              void* d_out, int out_size, void* d_ws, size_t ws_size,
                              hipStream_t stream) {
    const float* z          = (const float*)d_in[0];
    const float* z_next     = (const float*)d_in[1];
    const float* z_next_hat = (const float*)d_in[2];
    const float* actions    = (const float*)d_in[3];
    const float* Wa         = (const float*)d_in[4];
    const float* ba         = (const float*)d_in[5];
    const float* W1         = (const float*)d_in[6];
    const float* b1         = (const float*)d_in[7];
    const float* W2         = (const float*)d_in[8];
    const float* b2         = (const float*)d_in[9];
    float* out = (float*)d_out;

    float* ws  = (float*)d_ws;
    float* sim = ws;                         // 1024*1024
    float* u   = sim + B_SZ * B_SZ;          // 1024*512
    float* v   = u + B_SZ * ZH;              // 1024*512
    float* g   = v + B_SZ * ZH;              // 1024*512
    float* pw  = g + B_SZ * ZH;              // 1024*4
    unsigned* cnt = (unsigned*)(pw + B_SZ * 4);

    fused_gemm<<<640, 256, 0, stream>>>(z, z_next, z_next_hat, actions, Wa, ba,
                                        W1, b1, W2, sim, u, v, g, cnt);
    row_kernel<<<B_SZ, 256, 0, stream>>>(sim, u, v, g, z, z_next, b2, pw, cnt, out);
}

// Round 5
// 135.090 us; speedup vs baseline: 1.1676x; 1.1676x over previous
//
#include <hip/hip_runtime.h>
#include <math.h>

#define B_SZ 1024
#define Z_DIM 512
#define A_DIM 8
#define AH 64
#define ZH 512
#define NNEG 99
#define INV_T 10.0f

typedef __attribute__((ext_vector_type(8))) short short8;   // 8 bf16
typedef __attribute__((ext_vector_type(4))) float f32x4;

// fp32 -> bf16 hi (truncate) + bf16 lo (residual). x ~= hi+lo, rel err < 2^-16.
__device__ __forceinline__ void cvt8(float4 x0, float4 x1, short8& hi, short8& lo) {
    float xs[8] = {x0.x, x0.y, x0.z, x0.w, x1.x, x1.y, x1.z, x1.w};
#pragma unroll
    for (int i = 0; i < 8; ++i) {
        unsigned uu = __float_as_uint(xs[i]);
        hi[i] = (short)(uu >> 16);
        float hf = __uint_as_float(uu & 0xffff0000u);
        lo[i] = (short)(__float_as_uint(xs[i] - hf) >> 16);
    }
}
__device__ __forceinline__ void cvt8s(const float* xs, short8& hi, short8& lo) {
#pragma unroll
    for (int i = 0; i < 8; ++i) {
        unsigned uu = __float_as_uint(xs[i]);
        hi[i] = (short)(uu >> 16);
        float hf = __uint_as_float(uu & 0xffff0000u);
        lo[i] = (short)(__float_as_uint(xs[i] - hf) >> 16);
    }
}

// XOR-swizzled 16B-unit index into a [64 rows][8 kb] bf16 tile (no padding):
// staging writes and fragment reads are both <=2-way on banks (free, m136).
__device__ __forceinline__ int sw(int m, int kb) { return m * 8 + (kb ^ (m & 7)); }

struct MfmaSmem {
    short Ah[4096]; short Al[4096];                     // 8 KB each
    union {
        struct { short Bh[4096]; short Bl[4096]; } t;   // NT segs
        float Bn[64][68];                               // seg1 native W1 tile
    } b;
};
struct Seg3Smem {
    float LA[32][68]; float LB[32][68];
    float sact[64][A_DIM]; float sWa[A_DIM * AH]; float sba[AH];
};

// ---------------------------------------------------------------------------
// 640 blocks:
//   seg0 [  0,256): sim = z_next @ z_next_hat^T   (MFMA NT)
//   seg1 [256,384): u   = z @ W1[:512,:] + b1     (MFMA, B read native+strided LDS)
//   seg2 [384,512): v   = z_next @ W2^T           (MFMA NT)
//   seg3 [512,640): g   = relu(actions@Wa+ba)@W1h (fp32 vector, K=64)
__global__ __launch_bounds__(256) void fused_gemm(
    const float* __restrict__ z, const float* __restrict__ z_next,
    const float* __restrict__ z_next_hat, const float* __restrict__ actions,
    const float* __restrict__ Wa, const float* __restrict__ ba,
    const float* __restrict__ W1, const float* __restrict__ b1,
    const float* __restrict__ W2,
    float* __restrict__ sim, float* __restrict__ u, float* __restrict__ v,
    float* __restrict__ g, unsigned* __restrict__ cnt)
{
    __shared__ union { MfmaSmem m; Seg3Smem s; } sm;

    const int id = blockIdx.x;
    const int tid = threadIdx.x;
    if (id == 0 && tid == 0) atomicExch(cnt, 0u);

    // ================= seg3: g (fp32 vector path, K=64) =================
    if (id >= 512) {
        int t = id - 512;
        int bn0 = (t & 7) * 64, bm0 = (t >> 3) * 64;
        const float* W1h = W1 + Z_DIM * ZH;
        for (int i = tid; i < 64 * A_DIM; i += 256)
            (&sm.s.sact[0][0])[i] = actions[bm0 * A_DIM + i];
        for (int i = tid; i < A_DIM * AH; i += 256) sm.s.sWa[i] = Wa[i];
        if (tid < AH) sm.s.sba[tid] = ba[tid];
        __syncthreads();
        int tm = (tid >> 4) << 2, tn = (tid & 15) << 2;
        float acc[4][4] = {};
        for (int k0 = 0; k0 < 64; k0 += 32) {
#pragma unroll
            for (int i = 0; i < 8; ++i) {
                int lin = tid + i * 256;
                int c = lin & 31, r = lin >> 5;
                int kc = k0 + c;
                float val = sm.s.sba[kc];
#pragma unroll
                for (int k = 0; k < A_DIM; ++k) val += sm.s.sact[r][k] * sm.s.sWa[k * AH + kc];
                sm.s.LA[c][r] = fmaxf(val, 0.0f);
            }
#pragma unroll
            for (int i = 0; i < 2; ++i) {
                int f = tid + i * 256;
                int r = f >> 4, c = (f & 15) * 4;
                *(float4*)&sm.s.LB[r][c] = *(const float4*)&W1h[(k0 + r) * ZH + bn0 + c];
            }
            __syncthreads();
#pragma unroll
            for (int k = 0; k < 32; ++k) {
                float4 a4 = *(const float4*)&sm.s.LA[k][tm];
                float4 b4 = *(const float4*)&sm.s.LB[k][tn];
                float a[4] = {a4.x, a4.y, a4.z, a4.w};
                float b[4] = {b4.x, b4.y, b4.z, b4.w};
#pragma unroll
                for (int i = 0; i < 4; ++i)
#pragma unroll
                    for (int j = 0; j < 4; ++j) acc[i][j] += a[i] * b[j];
            }
            __syncthreads();
        }
#pragma unroll
        for (int i = 0; i < 4; ++i) {
            float4 o = {acc[i][0], acc[i][1], acc[i][2], acc[i][3]};
            *(float4*)&g[(bm0 + tm + i) * ZH + bn0 + tn] = o;
        }
        return;
    }

    // ================= MFMA segs =================
    const float* Aop; const float* Bop; const float* bias = nullptr;
    float* C; int N; bool btrans; int bm0, bn0;
    if (id < 256) {
        int t = id; bn0 = (t & 15) * 64; bm0 = (t >> 4) * 64;
        Aop = z_next; Bop = z_next_hat; C = sim; N = 1024; btrans = true;
    } else if (id < 384) {
        int t = id - 256; bn0 = (t & 7) * 64; bm0 = (t >> 3) * 64;
        Aop = z; Bop = W1; C = u; N = 512; btrans = false; bias = b1;
    } else {
        int t = id - 384; bn0 = (t & 7) * 64; bm0 = (t >> 3) * 64;
        Aop = z_next; Bop = W2; C = v; N = 512; btrans = true;
    }

    const int lane = tid & 63, wv = tid >> 6;
    const int lm = lane & 15, lq = lane >> 4;
    const int wm = (wv >> 1) * 32, wn = (wv & 1) * 32;
    const int sr = tid >> 2, sq = tid & 3;        // staging row / 16-float quarter
    short8* Ah8 = (short8*)sm.m.Ah; short8* Al8 = (short8*)sm.m.Al;
    short8* Bh8 = (short8*)sm.m.b.t.Bh; short8* Bl8 = (short8*)sm.m.b.t.Bl;
    f32x4 acc[2][2] = {};

    for (int k0 = 0; k0 < 512; k0 += 64) {
        {   // stage A: 16 consecutive floats of row sr -> kb 2sq, 2sq+1
            const float* base = &Aop[(bm0 + sr) * 512 + k0 + sq * 16];
            float4 x0 = *(const float4*)(base + 0), x1 = *(const float4*)(base + 4);
            float4 x2 = *(const float4*)(base + 8), x3 = *(const float4*)(base + 12);
            short8 h, l;
            cvt8(x0, x1, h, l); Ah8[sw(sr, 2 * sq)] = h;     Al8[sw(sr, 2 * sq)] = l;
            cvt8(x2, x3, h, l); Ah8[sw(sr, 2 * sq + 1)] = h; Al8[sw(sr, 2 * sq + 1)] = l;
        }
        if (btrans) {
            const float* base = &Bop[(bn0 + sr) * 512 + k0 + sq * 16];
            float4 x0 = *(const float4*)(base + 0), x1 = *(const float4*)(base + 4);
            float4 x2 = *(const float4*)(base + 8), x3 = *(const float4*)(base + 12);
            short8 h, l;
            cvt8(x0, x1, h, l); Bh8[sw(sr, 2 * sq)] = h;     Bl8[sw(sr, 2 * sq)] = l;
            cvt8(x2, x3, h, l); Bh8[sw(sr, 2 * sq + 1)] = h; Bl8[sw(sr, 2 * sq + 1)] = l;
        } else {
            // native-layout fp32 stage of the k-major W1 tile (b128, coalesced)
#pragma unroll
            for (int i = 0; i < 4; ++i) {
                int f = tid + i * 256;
                int kr = f >> 4, c4 = (f & 15) << 2;
                *(float4*)&sm.m.b.Bn[kr][c4] = *(const float4*)&Bop[(k0 + kr) * 512 + bn0 + c4];
            }
        }
        __syncthreads();
#pragma unroll
        for (int kk = 0; kk < 64; kk += 32) {
            int kbi = (kk >> 3) + lq;
            short8 ah[2], al[2], bh[2], bl[2];
#pragma unroll
            for (int i = 0; i < 2; ++i) {
                ah[i] = Ah8[sw(wm + i * 16 + lm, kbi)];
                al[i] = Al8[sw(wm + i * 16 + lm, kbi)];
            }
            if (btrans) {
#pragma unroll
                for (int j = 0; j < 2; ++j) {
                    bh[j] = Bh8[sw(wn + j * 16 + lm, kbi)];
                    bl[j] = Bl8[sw(wn + j * 16 + lm, kbi)];
                }
            } else {
                int kbase = kk + lq * 8;
#pragma unroll
                for (int j = 0; j < 2; ++j) {
                    int n = wn + j * 16 + lm;
                    float xv[8];
#pragma unroll
                    for (int jj = 0; jj < 8; ++jj) xv[jj] = sm.m.b.Bn[kbase + jj][n];
                    cvt8s(xv, bh[j], bl[j]);
                }
            }
#pragma unroll
            for (int i = 0; i < 2; ++i)
#pragma unroll
                for (int j = 0; j < 2; ++j) {
                    acc[i][j] = __builtin_amdgcn_mfma_f32_16x16x32_bf16(ah[i], bh[j], acc[i][j], 0, 0, 0);
                    acc[i][j] = __builtin_amdgcn_mfma_f32_16x16x32_bf16(ah[i], bl[j], acc[i][j], 0, 0, 0);
                    acc[i][j] = __builtin_amdgcn_mfma_f32_16x16x32_bf16(al[i], bh[j], acc[i][j], 0, 0, 0);
                }
        }
        __syncthreads();
    }
    // epilogue: C layout col=lane&15, row=(lane>>4)*4+reg
#pragma unroll
    for (int i = 0; i < 2; ++i)
#pragma unroll
        for (int j = 0; j < 2; ++j) {
            int n = bn0 + wn + j * 16 + lm;
            float bb = bias ? bias[n] : 0.0f;
#pragma unroll
            for (int r = 0; r < 4; ++r) {
                int m = bm0 + wm + i * 16 + lq * 4 + r;
                C[m * N + n] = acc[i][j][r] + bb;
            }
        }
}

// ---------------------------------------------------------------------------
// 256 blocks x 4 rows. Phase 1: g-rows staged once per block (batches of 8),
// shared by 4 waves; 8 independent dot-chains hide shfl latency.
// Phase 2: per-wave softmax/rank (no cross-wave syncs). Last block finalizes.
__global__ __launch_bounds__(256) void row2_kernel(
    const float* __restrict__ sim, const float* __restrict__ u,
    const float* __restrict__ v, const float* __restrict__ g,
    const float* __restrict__ z, const float* __restrict__ z_next,
    const float* __restrict__ b2,
    float* __restrict__ pw, unsigned* __restrict__ cnt, float* __restrict__ out)
{
    const int blk = blockIdx.x;
    const int tid = threadIdx.x;
    const int w = tid >> 6, lane = tid & 63;
    const int b = blk * 4 + w;                 // row owned by this wave
    __shared__ float gbuf[8][512];
    __shared__ float rn[4][100];
    __shared__ float sacc[4][4];
    __shared__ float red[256];
    __shared__ int sdone;

    // per-lane u,v fragments: elems [4*lane,4*lane+4) and [256+4*lane, ...)
    float4 ua = *(const float4*)&u[b * 512 + lane * 4];
    float4 ub = *(const float4*)&u[b * 512 + 256 + lane * 4];
    float4 va = *(const float4*)&v[b * 512 + lane * 4];
    float4 vb = *(const float4*)&v[b * 512 + 256 + lane * 4];

    // c0 = (z[b]+b2) . z_next[b]
    float p;
    {
        float4 za = *(const float4*)&z[b * 512 + lane * 4];
        float4 zb = *(const float4*)&z[b * 512 + 256 + lane * 4];
        float4 na = *(const float4*)&z_next[b * 512 + lane * 4];
        float4 nb = *(const float4*)&z_next[b * 512 + 256 + lane * 4];
        float4 ca = *(const float4*)&b2[lane * 4];
        float4 cb = *(const float4*)&b2[256 + lane * 4];
        p  = (za.x + ca.x) * na.x + (za.y + ca.y) * na.y + (za.z + ca.z) * na.z + (za.w + ca.w) * na.w;
        p += (zb.x + cb.x) * nb.x + (zb.y + cb.y) * nb.y + (zb.z + cb.z) * nb.z + (zb.w + cb.w) * nb.w;
    }
    for (int off = 32; off; off >>= 1) p += __shfl_down(p, off);
    float c0 = __shfl(p, 0);

    const int J0 = blk * 4;                    // jr = J0 + 1 + idx, idx in [0,102)
    for (int it = 0; it < 13; ++it) {
#pragma unroll
        for (int ph = 0; ph < 4; ++ph) {       // stage up to 8 g rows
            int f4i = tid + ph * 256;          // 0..1023
            int row = f4i >> 7, c = f4i & 127;
            int idx = it * 8 + row;
            if (idx < 102) {
                int jr = (J0 + 1 + idx) & (B_SZ - 1);
                *(float4*)&gbuf[row][c * 4] = *(const float4*)&g[jr * 512 + c * 4];
            }
        }
        __syncthreads();
        float d[8];
#pragma unroll
        for (int ri = 0; ri < 8; ++ri) {
            float4 g0 = *(const float4*)&gbuf[ri][lane * 4];
            float4 g1 = *(const float4*)&gbuf[ri][256 + lane * 4];
            float t = 0.0f;
            t += fmaxf(ua.x + g0.x, 0.0f) * va.x;
            t += fmaxf(ua.y + g0.y, 0.0f) * va.y;
            t += fmaxf(ua.z + g0.z, 0.0f) * va.z;
            t += fmaxf(ua.w + g0.w, 0.0f) * va.w;
            t += fmaxf(ub.x + g1.x, 0.0f) * vb.x;
            t += fmaxf(ub.y + g1.y, 0.0f) * vb.y;
            t += fmaxf(ub.z + g1.z, 0.0f) * vb.z;
            t += fmaxf(ub.w + g1.w, 0.0f) * vb.w;
            d[ri] = t;
        }
        for (int off = 32; off; off >>= 1) {
#pragma unroll
            for (int ri = 0; ri < 8; ++ri) d[ri] += __shfl_down(d[ri], off);
        }
        if (lane == 0) {
#pragma unroll
            for (int ri = 0; ri < 8; ++ri) {
                int idx = it * 8 + ri;
                int s1 = idx - w;              // s-1
                if (idx < 102 && s1 >= 0 && s1 < 99) rn[w][s1] = c0 + d[ri];
            }
        }
        __syncthreads();
    }

    // -------- phase 2: per-wave softmax + rank on row b --------
    float4 sv[4];
#pragma unroll
    for (int i = 0; i < 4; ++i)
        sv[i] = *(const float4*)&sim[b * 1024 + lane * 16 + i * 4];
    float nva = rn[w][lane];
    float nvb = (lane < 35) ? rn[w][lane + 64] : -3.4e38f;
    float diag = sim[b * 1024 + b];

    float m = fmaxf(nva, nvb);
#pragma unroll
    for (int i = 0; i < 4; ++i)
        m = fmaxf(m, fmaxf(fmaxf(sv[i].x, sv[i].y), fmaxf(sv[i].z, sv[i].w)));
    for (int off = 32; off; off >>= 1) m = fmaxf(m, __shfl_xor(m, off));

    float es = 0.0f; int ck = 0;
#pragma unroll
    for (int i = 0; i < 4; ++i) {
        float xs[4] = {sv[i].x, sv[i].y, sv[i].z, sv[i].w};
#pragma unroll
        for (int c = 0; c < 4; ++c) {
            int j = lane * 16 + i * 4 + c;
            float x = xs[c];
            es += __expf((x - m) * INV_T);
            if (x > diag) ck++;
            else if (j < b && x == diag) ck++;  // tie-break: lower index wins
        }
    }
    es += __expf((nva - m) * INV_T);
    if (nva > diag) ck++;
    if (lane < 35) {
        es += __expf((nvb - m) * INV_T);
        if (nvb > diag) ck++;
    }
    for (int off = 32; off; off >>= 1) {
        es += __shfl_down(es, off);
        ck += __shfl_down(ck, off);
    }
    if (lane == 0) {
        float loss_b = (m - diag) * INV_T + logf(es);
        sacc[w][0] = loss_b;
        sacc[w][1] = (ck < 1) ? 1.0f : 0.0f;
        sacc[w][2] = (ck < 3) ? 1.0f : 0.0f;
        sacc[w][3] = (ck < 10) ? 1.0f : 0.0f;
    }
    __syncthreads();
    if (tid == 0) {
#pragma unroll
        for (int c = 0; c < 4; ++c)
            pw[blk * 4 + c] = sacc[0][c] + sacc[1][c] + sacc[2][c] + sacc[3][c];
        __threadfence();
        unsigned old = atomicAdd(cnt, 1u);
        sdone = (old == 255u) ? 1 : 0;
    }
    __syncthreads();
    if (sdone) {
        __threadfence();
        int c = tid & 3;
        float s = 0.0f;
        for (int r = tid >> 2; r < 256; r += 64) s += pw[r * 4 + c];
        red[tid] = s;
        __syncthreads();
        if (tid < 4) {
            float t = 0.0f;
            for (int q = 0; q < 64; ++q) t += red[tid + q * 4];
            out[tid] = t * (1.0f / (float)B_SZ);
        }
    }
}

// ---------------------------------------------------------------------------
extern "C" void kernel_launch(void* const* d_in, const int* in_sizes, int n_in,
                              void* d_out, int out_size, void* d_ws, size_t ws_size,
                              hipStream_t stream) {
    const float* z          = (const float*)d_in[0];
    const float* z_next     = (const float*)d_in[1];
    const float* z_next_hat = (const float*)d_in[2];
    const float* actions    = (const float*)d_in[3];
    const float* Wa         = (const float*)d_in[4];
    const float* ba         = (const float*)d_in[5];
    const float* W1         = (const float*)d_in[6];
    const float* b1         = (const float*)d_in[7];
    const float* W2         = (const float*)d_in[8];
    const float* b2         = (const float*)d_in[9];
    float* out = (float*)d_out;

    float* ws  = (float*)d_ws;
    float* sim = ws;                         // 1024*1024
    float* u   = sim + B_SZ * B_SZ;          // 1024*512
    float* v   = u + B_SZ * ZH;              // 1024*512
    float* g   = v + B_SZ * ZH;              // 1024*512
    float* pw  = g + B_SZ * ZH;              // 256*4
    unsigned* cnt = (unsigned*)(pw + 256 * 4);

    fused_gemm<<<640, 256, 0, stream>>>(z, z_next, z_next_hat, actions, Wa, ba,
                                        W1, b1, W2, sim, u, v, g, cnt);
    row2_kernel<<<256, 256, 0, stream>>>(sim, u, v, g, z, z_next, b2, pw, cnt, out);
}

// Round 6
// 124.059 us; speedup vs baseline: 1.2715x; 1.0889x over previous
//
#include <hip/hip_runtime.h>
#include <math.h>

#define B_SZ 1024
#define Z_DIM 512
#define A_DIM 8
#define AH 64
#define ZH 512
#define NNEG 99
#define INV_T 10.0f

typedef __attribute__((ext_vector_type(8))) short short8;   // 8 bf16 (16 B)
typedef __attribute__((ext_vector_type(4))) float f32x4;

// fp32 -> bf16 hi (truncate) + bf16 lo (residual). x ~= hi+lo, rel err < 2^-16.
__device__ __forceinline__ void cvt8(float4 x0, float4 x1, short8& hi, short8& lo) {
    float xs[8] = {x0.x, x0.y, x0.z, x0.w, x1.x, x1.y, x1.z, x1.w};
#pragma unroll
    for (int i = 0; i < 8; ++i) {
        unsigned uu = __float_as_uint(xs[i]);
        hi[i] = (short)(uu >> 16);
        float hf = __uint_as_float(uu & 0xffff0000u);
        lo[i] = (short)(__float_as_uint(xs[i] - hf) >> 16);
    }
}

// XOR-swizzled 16B-unit index into a [64 rows][8 units] bf16 tile (no padding).
__device__ __forceinline__ int sw(int m, int kb) { return m * 8 + (kb ^ (m & 7)); }

// ---------------------------------------------------------------------------
// prep: blocks [0,72) transpose W1 [576][512] -> W1T [512][576];
//       blocks [72,88) compute ha = relu(actions@Wa+ba)  [1024][64];
//       block 0 resets cnt.
__global__ __launch_bounds__(256) void prep_kernel(
    const float* __restrict__ W1, const float* __restrict__ actions,
    const float* __restrict__ Wa, const float* __restrict__ ba,
    float* __restrict__ W1T, float* __restrict__ ha, unsigned* __restrict__ cnt)
{
    const int id = blockIdx.x, tid = threadIdx.x;
    if (id == 0 && tid == 0) atomicExch(cnt, 0u);
    if (id < 72) {
        __shared__ float L[64][68];
        int kt = id >> 3, nt = id & 7;
#pragma unroll
        for (int i = 0; i < 4; ++i) {
            int f = tid + i * 256;
            int r = f >> 4, c4 = (f & 15) << 2;
            *(float4*)&L[r][c4] = *(const float4*)&W1[(kt * 64 + r) * 512 + nt * 64 + c4];
        }
        __syncthreads();
#pragma unroll
        for (int i = 0; i < 4; ++i) {
            int f = tid + i * 256;
            int r = f >> 4, c4 = (f & 15) << 2;   // out row r (n), cols c4.. (k)
            float4 o = {L[c4][r], L[c4 + 1][r], L[c4 + 2][r], L[c4 + 3][r]};
            *(float4*)&W1T[(nt * 64 + r) * 576 + kt * 64 + c4] = o;
        }
    } else if (id < 88) {
        __shared__ float sWa[A_DIM * 64];
        __shared__ float sba[64];
        __shared__ float sact[64][A_DIM];
        int j0 = (id - 72) * 64;
        for (int i = tid; i < A_DIM * 64; i += 256) sWa[i] = Wa[i];
        if (tid < 64) sba[tid] = ba[tid];
        for (int i = tid; i < 64 * A_DIM; i += 256) (&sact[0][0])[i] = actions[j0 * A_DIM + i];
        __syncthreads();
        int r = tid >> 2, c0 = (tid & 3) * 16;
        float o[16];
#pragma unroll
        for (int c = 0; c < 16; ++c) o[c] = sba[c0 + c];
#pragma unroll
        for (int k = 0; k < A_DIM; ++k) {
            float a = sact[r][k];
#pragma unroll
            for (int c = 0; c < 16; ++c) o[c] += a * sWa[k * 64 + c0 + c];
        }
#pragma unroll
        for (int c = 0; c < 16; c += 4) {
            float4 v4 = {fmaxf(o[c], 0.f), fmaxf(o[c + 1], 0.f),
                         fmaxf(o[c + 2], 0.f), fmaxf(o[c + 3], 0.f)};
            *(float4*)&ha[(j0 + r) * 64 + c0 + c] = v4;
        }
    }
}

// ---------------------------------------------------------------------------
// Uniform NT MFMA GEMM, 640 blocks (one code path for all segments):
//   seg0 [  0,256): sim = z_next @ z_next_hat^T [1024x1024 K=512]
//   seg1 [256,384): u   = z @ W1T[:, :512]^T+b1 [1024x512  K=512]
//   seg2 [384,512): v   = z_next @ W2^T         [1024x512  K=512]
//   seg3 [512,640): g   = ha @ W1T[:,512:]^T    [1024x512  K=64]
// 64x64 tile, 4 waves x 32x32 (2x2 of 16x16x32 bf16), hi/lo 3-term split,
// cvt once at staging, swizzled bf16 LDS, b128 fragment reads.
__global__ __launch_bounds__(256) void mm_kernel(
    const float* __restrict__ z, const float* __restrict__ z_next,
    const float* __restrict__ z_next_hat, const float* __restrict__ W1T,
    const float* __restrict__ b1, const float* __restrict__ W2,
    const float* __restrict__ ha,
    float* __restrict__ sim, float* __restrict__ u, float* __restrict__ v,
    float* __restrict__ g)
{
    __shared__ short Ah[4096], Al[4096], Bh[4096], Bl[4096];   // 32 KB

    const int id = blockIdx.x;
    const int tid = threadIdx.x;

    const float* Aop; const float* Bop; const float* bias = nullptr;
    float* C; int N, K, lda, ldb, bm0, bn0;
    if (id < 256) {
        int t = id; bn0 = (t & 15) * 64; bm0 = (t >> 4) * 64;
        Aop = z_next; lda = 512; Bop = z_next_hat; ldb = 512;
        C = sim; N = 1024; K = 512;
    } else if (id < 384) {
        int t = id - 256; bn0 = (t & 7) * 64; bm0 = (t >> 3) * 64;
        Aop = z; lda = 512; Bop = W1T; ldb = 576;
        C = u; N = 512; K = 512; bias = b1;
    } else if (id < 512) {
        int t = id - 384; bn0 = (t & 7) * 64; bm0 = (t >> 3) * 64;
        Aop = z_next; lda = 512; Bop = W2; ldb = 512;
        C = v; N = 512; K = 512;
    } else {
        int t = id - 512; bn0 = (t & 7) * 64; bm0 = (t >> 3) * 64;
        Aop = ha; lda = 64; Bop = W1T + 512; ldb = 576;
        C = g; N = 512; K = 64;
    }

    const int lane = tid & 63, wv = tid >> 6;
    const int lm = lane & 15, lq = lane >> 4;
    const int wm = (wv >> 1) * 32, wn = (wv & 1) * 32;
    const int sr = tid >> 2, sq = tid & 3;     // staging: row, 16-float quarter
    short8* Ah8 = (short8*)Ah; short8* Al8 = (short8*)Al;
    short8* Bh8 = (short8*)Bh; short8* Bl8 = (short8*)Bl;
    f32x4 acc[2][2] = {};

    for (int k0 = 0; k0 < K; k0 += 64) {
        {   // A: 16 consecutive floats of row sr -> units 2sq, 2sq+1
            const float* base = &Aop[(bm0 + sr) * lda + k0 + sq * 16];
            float4 x0 = *(const float4*)(base + 0), x1 = *(const float4*)(base + 4);
            float4 x2 = *(const float4*)(base + 8), x3 = *(const float4*)(base + 12);
            short8 h, l;
            cvt8(x0, x1, h, l); Ah8[sw(sr, 2 * sq)] = h;     Al8[sw(sr, 2 * sq)] = l;
            cvt8(x2, x3, h, l); Ah8[sw(sr, 2 * sq + 1)] = h; Al8[sw(sr, 2 * sq + 1)] = l;
        }
        {   // B: same, NT layout
            const float* base = &Bop[(bn0 + sr) * ldb + k0 + sq * 16];
            float4 x0 = *(const float4*)(base + 0), x1 = *(const float4*)(base + 4);
            float4 x2 = *(const float4*)(base + 8), x3 = *(const float4*)(base + 12);
            short8 h, l;
            cvt8(x0, x1, h, l); Bh8[sw(sr, 2 * sq)] = h;     Bl8[sw(sr, 2 * sq)] = l;
            cvt8(x2, x3, h, l); Bh8[sw(sr, 2 * sq + 1)] = h; Bl8[sw(sr, 2 * sq + 1)] = l;
        }
        __syncthreads();
#pragma unroll
        for (int kk = 0; kk < 64; kk += 32) {
            int kbi = (kk >> 3) + lq;
            short8 ah[2], al[2], bh[2], bl[2];
#pragma unroll
            for (int i = 0; i < 2; ++i) {
                ah[i] = Ah8[sw(wm + i * 16 + lm, kbi)];
                al[i] = Al8[sw(wm + i * 16 + lm, kbi)];
                bh[i] = Bh8[sw(wn + i * 16 + lm, kbi)];
                bl[i] = Bl8[sw(wn + i * 16 + lm, kbi)];
            }
#pragma unroll
            for (int i = 0; i < 2; ++i)
#pragma unroll
                for (int j = 0; j < 2; ++j) {
                    acc[i][j] = __builtin_amdgcn_mfma_f32_16x16x32_bf16(ah[i], bh[j], acc[i][j], 0, 0, 0);
                    acc[i][j] = __builtin_amdgcn_mfma_f32_16x16x32_bf16(ah[i], bl[j], acc[i][j], 0, 0, 0);
                    acc[i][j] = __builtin_amdgcn_mfma_f32_16x16x32_bf16(al[i], bh[j], acc[i][j], 0, 0, 0);
                }
        }
        __syncthreads();
    }
    // epilogue: C layout col=lane&15, row=(lane>>4)*4+reg
#pragma unroll
    for (int i = 0; i < 2; ++i)
#pragma unroll
        for (int j = 0; j < 2; ++j) {
            int n = bn0 + wn + j * 16 + lm;
            float bb = bias ? bias[n] : 0.0f;
#pragma unroll
            for (int r = 0; r < 4; ++r) {
                int m = bm0 + wm + i * 16 + lq * 4 + r;
                C[m * N + n] = acc[i][j][r] + bb;
            }
        }
}

// ---------------------------------------------------------------------------
// 256 blocks x 4 rows. Phase 1: g-rows staged once per block (batches of 8),
// shared by 4 waves; 8 independent dot-chains hide shfl latency.
// Phase 2: per-wave softmax/rank. Last block finalizes.
__global__ __launch_bounds__(256) void row2_kernel(
    const float* __restrict__ sim, const float* __restrict__ u,
    const float* __restrict__ v, const float* __restrict__ g,
    const float* __restrict__ z, const float* __restrict__ z_next,
    const float* __restrict__ b2,
    float* __restrict__ pw, unsigned* __restrict__ cnt, float* __restrict__ out)
{
    const int blk = blockIdx.x;
    const int tid = threadIdx.x;
    const int w = tid >> 6, lane = tid & 63;
    const int b = blk * 4 + w;
    __shared__ float gbuf[8][512];
    __shared__ float rn[4][100];
    __shared__ float sacc[4][4];
    __shared__ float red[256];
    __shared__ int sdone;

    float4 ua = *(const float4*)&u[b * 512 + lane * 4];
    float4 ub = *(const float4*)&u[b * 512 + 256 + lane * 4];
    float4 va = *(const float4*)&v[b * 512 + lane * 4];
    float4 vb = *(const float4*)&v[b * 512 + 256 + lane * 4];

    float p;
    {
        float4 za = *(const float4*)&z[b * 512 + lane * 4];
        float4 zb = *(const float4*)&z[b * 512 + 256 + lane * 4];
        float4 na = *(const float4*)&z_next[b * 512 + lane * 4];
        float4 nb = *(const float4*)&z_next[b * 512 + 256 + lane * 4];
        float4 ca = *(const float4*)&b2[lane * 4];
        float4 cb = *(const float4*)&b2[256 + lane * 4];
        p  = (za.x + ca.x) * na.x + (za.y + ca.y) * na.y + (za.z + ca.z) * na.z + (za.w + ca.w) * na.w;
        p += (zb.x + cb.x) * nb.x + (zb.y + cb.y) * nb.y + (zb.z + cb.z) * nb.z + (zb.w + cb.w) * nb.w;
    }
    for (int off = 32; off; off >>= 1) p += __shfl_down(p, off);
    float c0 = __shfl(p, 0);

    const int J0 = blk * 4;
    for (int it = 0; it < 13; ++it) {
#pragma unroll
        for (int ph = 0; ph < 4; ++ph) {
            int f4i = tid + ph * 256;
            int row = f4i >> 7, c = f4i & 127;
            int idx = it * 8 + row;
            if (idx < 102) {
                int jr = (J0 + 1 + idx) & (B_SZ - 1);
                *(float4*)&gbuf[row][c * 4] = *(const float4*)&g[jr * 512 + c * 4];
            }
        }
        __syncthreads();
        float d[8];
#pragma unroll
        for (int ri = 0; ri < 8; ++ri) {
            float4 g0 = *(const float4*)&gbuf[ri][lane * 4];
            float4 g1 = *(const float4*)&gbuf[ri][256 + lane * 4];
            float t = 0.0f;
            t += fmaxf(ua.x + g0.x, 0.0f) * va.x;
            t += fmaxf(ua.y + g0.y, 0.0f) * va.y;
            t += fmaxf(ua.z + g0.z, 0.0f) * va.z;
            t += fmaxf(ua.w + g0.w, 0.0f) * va.w;
            t += fmaxf(ub.x + g1.x, 0.0f) * vb.x;
            t += fmaxf(ub.y + g1.y, 0.0f) * vb.y;
            t += fmaxf(ub.z + g1.z, 0.0f) * vb.z;
            t += fmaxf(ub.w + g1.w, 0.0f) * vb.w;
            d[ri] = t;
        }
        for (int off = 32; off; off >>= 1) {
#pragma unroll
            for (int ri = 0; ri < 8; ++ri) d[ri] += __shfl_down(d[ri], off);
        }
        if (lane == 0) {
#pragma unroll
            for (int ri = 0; ri < 8; ++ri) {
                int idx = it * 8 + ri;
                int s1 = idx - w;
                if (idx < 102 && s1 >= 0 && s1 < 99) rn[w][s1] = c0 + d[ri];
            }
        }
        __syncthreads();
    }

    // phase 2
    float4 sv[4];
#pragma unroll
    for (int i = 0; i < 4; ++i)
        sv[i] = *(const float4*)&sim[b * 1024 + lane * 16 + i * 4];
    float nva = rn[w][lane];
    float nvb = (lane < 35) ? rn[w][lane + 64] : -3.4e38f;
    float diag = sim[b * 1024 + b];

    float m = fmaxf(nva, nvb);
#pragma unroll
    for (int i = 0; i < 4; ++i)
        m = fmaxf(m, fmaxf(fmaxf(sv[i].x, sv[i].y), fmaxf(sv[i].z, sv[i].w)));
    for (int off = 32; off; off >>= 1) m = fmaxf(m, __shfl_xor(m, off));

    float es = 0.0f; int ck = 0;
#pragma unroll
    for (int i = 0; i < 4; ++i) {
        float xs[4] = {sv[i].x, sv[i].y, sv[i].z, sv[i].w};
#pragma unroll
        for (int c = 0; c < 4; ++c) {
            int j = lane * 16 + i * 4 + c;
            float x = xs[c];
            es += __expf((x - m) * INV_T);
            if (x > diag) ck++;
            else if (j < b && x == diag) ck++;
        }
    }
    es += __expf((nva - m) * INV_T);
    if (nva > diag) ck++;
    if (lane < 35) {
        es += __expf((nvb - m) * INV_T);
        if (nvb > diag) ck++;
    }
    for (int off = 32; off; off >>= 1) {
        es += __shfl_down(es, off);
        ck += __shfl_down(ck, off);
    }
    if (lane == 0) {
        float loss_b = (m - diag) * INV_T + logf(es);
        sacc[w][0] = loss_b;
        sacc[w][1] = (ck < 1) ? 1.0f : 0.0f;
        sacc[w][2] = (ck < 3) ? 1.0f : 0.0f;
        sacc[w][3] = (ck < 10) ? 1.0f : 0.0f;
    }
    __syncthreads();
    if (tid == 0) {
#pragma unroll
        for (int c = 0; c < 4; ++c)
            pw[blk * 4 + c] = sacc[0][c] + sacc[1][c] + sacc[2][c] + sacc[3][c];
        __threadfence();
        unsigned old = atomicAdd(cnt, 1u);
        sdone = (old == 255u) ? 1 : 0;
    }
    __syncthreads();
    if (sdone) {
        __threadfence();
        int c = tid & 3;
        float s = 0.0f;
        for (int r = tid >> 2; r < 256; r += 64) s += pw[r * 4 + c];
        red[tid] = s;
        __syncthreads();
        if (tid < 4) {
            float t = 0.0f;
            for (int q = 0; q < 64; ++q) t += red[tid + q * 4];
            out[tid] = t * (1.0f / (float)B_SZ);
        }
    }
}

// ---------------------------------------------------------------------------
extern "C" void kernel_launch(void* const* d_in, const int* in_sizes, int n_in,
                              void* d_out, int out_size, void* d_ws, size_t ws_size,
                              hipStream_t stream) {
    const float* z          = (const float*)d_in[0];
    const float* z_next     = (const float*)d_in[1];
    const float* z_next_hat = (const float*)d_in[2];
    const float* actions    = (const float*)d_in[3];
    const float* Wa         = (const float*)d_in[4];
    const float* ba         = (const float*)d_in[5];
    const float* W1         = (const float*)d_in[6];
    const float* b1         = (const float*)d_in[7];
    const float* W2         = (const float*)d_in[8];
    const float* b2         = (const float*)d_in[9];
    float* out = (float*)d_out;

    float* ws   = (float*)d_ws;
    float* sim  = ws;                          // 1024*1024
    float* u    = sim + B_SZ * B_SZ;           // 1024*512
    float* v    = u + B_SZ * ZH;               // 1024*512
    float* g    = v + B_SZ * ZH;               // 1024*512
    float* W1T  = g + B_SZ * ZH;               // 512*576
    float* ha   = W1T + 512 * 576;             // 1024*64
    float* pw   = ha + B_SZ * AH;              // 256*4
    unsigned* cnt = (unsigned*)(pw + 256 * 4);

    prep_kernel<<<88, 256, 0, stream>>>(W1, actions, Wa, ba, W1T, ha, cnt);
    mm_kernel<<<640, 256, 0, stream>>>(z, z_next, z_next_hat, W1T, b1, W2, ha,
                                       sim, u, v, g);
    row2_kernel<<<256, 256, 0, stream>>>(sim, u, v, g, z, z_next, b2, pw, cnt, out);
}